// Round 3
// baseline (691.180 us; speedup 1.0000x reference)
//
#include <hip/hip_runtime.h>
#include <hip/hip_bf16.h>

typedef unsigned short u16;
typedef __bf16 bf16x8 __attribute__((ext_vector_type(8)));
typedef float f32x4 __attribute__((ext_vector_type(4)));

#define N_NODES 200000
#define IN_FEAT 500
#define EMB 128
#define HID 64
#define NC 7
#define BM 64          // rows per block
#define BK 64          // k-chunk (8 chunks of 64; 500 zero-padded to 512)
#define KPAD 512

// LDS strides (bf16 elements). FS=72: row stride 144B -> rows r and r+8 share
// banks (2-way, free); fragment reads 16B-aligned.
#define FS 72          // F chunk  [64][72]
#define ES 136         // emb tile [64][136]
#define HS 72          // h tile   [64][72]

// d_ws layout (u16): Wt_emb[128][512] | Wt1[64][128] | Wt2[16][64]
#define WS_WT1_OFF (128*512)
#define WS_WT2_OFF (128*512 + 64*128)
#define WS_TOTAL   (128*512 + 64*128 + 16*64)

__device__ __forceinline__ u16 cvt_bf16(float v) {
    __hip_bfloat16 h = __float2bfloat16(v);
    return *(u16*)&h;
}

__global__ __launch_bounds__(256) void prep_weights(
    const float* __restrict__ W_emb, const float* __restrict__ W_rt1,
    const float* __restrict__ W_rt2, u16* __restrict__ ws)
{
    int idx = blockIdx.x * 256 + threadIdx.x;
    float v;
    bool ok = true;
    if (idx < 128*512) {                       // Wt_emb[n][k], zero-pad k>=500
        int n = idx >> 9, k = idx & 511;
        v = (k < IN_FEAT) ? W_emb[k*EMB + n] : 0.f;
    } else if (idx < WS_WT2_OFF) {             // Wt1[n][k]
        int j = idx - WS_WT1_OFF;
        int n = j >> 7, k = j & 127;
        v = W_rt1[k*HID + n];
    } else if (idx < WS_TOTAL) {               // Wt2[n][k], zero-pad n>=7
        int j = idx - WS_WT2_OFF;
        int n = j >> 6, k = j & 63;
        v = (n < NC) ? W_rt2[k*NC + n] : 0.f;
    } else { ok = false; v = 0.f; }
    if (ok) ws[idx] = cvt_bf16(v);
}

__global__ __launch_bounds__(256, 4) void mlp_fused(
    const float* __restrict__ F, const u16* __restrict__ Wt_emb,
    const u16* __restrict__ Wt1g, const u16* __restrict__ Wt2g,
    const float* __restrict__ b_emb, const float* __restrict__ b1,
    const float* __restrict__ b2, float* __restrict__ out)
{
    __shared__ u16 Fch[BM * FS];   //  9.2 KB
    __shared__ u16 Et[BM * ES];    // 17.4 KB
    __shared__ u16 Ht[BM * HS];    //  9.2 KB  -> total 35 KB => 4 blocks/CU

    const int tid  = threadIdx.x;
    const int wave = tid >> 6;
    const int lane = tid & 63;
    const int l15  = lane & 15;
    const int q    = lane >> 4;            // quad 0..3
    const int row0 = blockIdx.x * BM;

    // F staging map: thread -> row r = tid>>2, 16-float group g = tid&3
    const int r = tid >> 2, g = tid & 3;
    const float* Frow = F + (size_t)(row0 + r) * IN_FEAT + g * 16;

    // ---- layer 1: emb = relu(F @ W_emb + b_emb) over 8 chunks of K=64 ----
    f32x4 acc[8];
    #pragma unroll
    for (int t = 0; t < 8; ++t) acc[t] = (f32x4){0.f,0.f,0.f,0.f};

    float4 pf0, pf1, pf2, pf3;
    // prefetch chunk 0 (fully in-bounds)
    pf0 = *(const float4*)(Frow + 0);
    pf1 = *(const float4*)(Frow + 4);
    pf2 = *(const float4*)(Frow + 8);
    pf3 = *(const float4*)(Frow + 12);

    for (int c = 0; c < 8; ++c) {
        // convert + write the prefetched chunk into LDS
        union { u16 u[16]; uint4 v4[2]; } pk;
        pk.u[0]=cvt_bf16(pf0.x); pk.u[1]=cvt_bf16(pf0.y); pk.u[2]=cvt_bf16(pf0.z); pk.u[3]=cvt_bf16(pf0.w);
        pk.u[4]=cvt_bf16(pf1.x); pk.u[5]=cvt_bf16(pf1.y); pk.u[6]=cvt_bf16(pf1.z); pk.u[7]=cvt_bf16(pf1.w);
        pk.u[8]=cvt_bf16(pf2.x); pk.u[9]=cvt_bf16(pf2.y); pk.u[10]=cvt_bf16(pf2.z); pk.u[11]=cvt_bf16(pf2.w);
        pk.u[12]=cvt_bf16(pf3.x); pk.u[13]=cvt_bf16(pf3.y); pk.u[14]=cvt_bf16(pf3.z); pk.u[15]=cvt_bf16(pf3.w);
        if (c > 0) __syncthreads();            // prior chunk's reads complete
        *(uint4*)&Fch[r*FS + g*16]     = pk.v4[0];
        *(uint4*)&Fch[r*FS + g*16 + 8] = pk.v4[1];
        __syncthreads();

        // prefetch chunk c+1 (overlaps with MFMA phase below)
        if (c < 7) {
            const float* src = Frow + (c + 1) * BK;
            if (c < 6) {                       // fully in-bounds
                pf0 = *(const float4*)(src + 0);
                pf1 = *(const float4*)(src + 4);
                pf2 = *(const float4*)(src + 8);
                pf3 = *(const float4*)(src + 12);
            } else {                           // chunk 7: k0=448, valid k<500
                // g<3: all 16 valid; g==3: only first float4 (k 496..499)
                pf0 = *(const float4*)(src + 0);
                pf1 = (g < 3) ? *(const float4*)(src + 4)  : make_float4(0,0,0,0);
                pf2 = (g < 3) ? *(const float4*)(src + 8)  : make_float4(0,0,0,0);
                pf3 = (g < 3) ? *(const float4*)(src + 12) : make_float4(0,0,0,0);
            }
        }

        // MFMA phase: A-frags from LDS, B-frags direct from L2-hot global
        #pragma unroll
        for (int sub = 0; sub < 2; ++sub) {
            bf16x8 a = *(const bf16x8*)&Fch[(wave*16 + l15)*FS + sub*32 + q*8];
            const u16* wb = Wt_emb + l15*KPAD + c*BK + sub*32 + q*8;
            #pragma unroll
            for (int t = 0; t < 8; ++t) {
                bf16x8 b = *(const bf16x8*)(wb + t*16*KPAD);
                acc[t] = __builtin_amdgcn_mfma_f32_16x16x32_bf16(a, b, acc[t], 0, 0, 0);
            }
        }
    }
    __syncthreads();

    // epilogue 1: bias + relu -> bf16 emb tile in LDS
    #pragma unroll
    for (int t = 0; t < 8; ++t) {
        float bias = b_emb[t*16 + l15];
        #pragma unroll
        for (int rr = 0; rr < 4; ++rr) {
            float v = acc[t][rr] + bias;
            v = v > 0.f ? v : 0.f;
            Et[(wave*16 + q*4 + rr)*ES + t*16 + l15] = cvt_bf16(v);
        }
    }
    __syncthreads();

    // ---- layer 2: h = relu(emb @ W_rt1 + b1), K=128; B direct from global ----
    f32x4 acc2[4];
    #pragma unroll
    for (int t = 0; t < 4; ++t) acc2[t] = (f32x4){0.f,0.f,0.f,0.f};
    #pragma unroll
    for (int kc = 0; kc < 4; ++kc) {
        bf16x8 a = *(const bf16x8*)&Et[(wave*16 + l15)*ES + kc*32 + q*8];
        #pragma unroll
        for (int t = 0; t < 4; ++t) {
            bf16x8 b = *(const bf16x8*)&Wt1g[(t*16 + l15)*128 + kc*32 + q*8];
            acc2[t] = __builtin_amdgcn_mfma_f32_16x16x32_bf16(a, b, acc2[t], 0, 0, 0);
        }
    }
    #pragma unroll
    for (int t = 0; t < 4; ++t) {
        float bias = b1[t*16 + l15];
        #pragma unroll
        for (int rr = 0; rr < 4; ++rr) {
            float v = acc2[t][rr] + bias;
            v = v > 0.f ? v : 0.f;
            Ht[(wave*16 + q*4 + rr)*HS + t*16 + l15] = cvt_bf16(v);
        }
    }
    __syncthreads();

    // ---- layer 3: out = h @ W_rt2 + b2, K=64, N=7 (padded 16) ----
    f32x4 acc3 = (f32x4){0.f,0.f,0.f,0.f};
    #pragma unroll
    for (int kc = 0; kc < 2; ++kc) {
        bf16x8 a = *(const bf16x8*)&Ht[(wave*16 + l15)*HS + kc*32 + q*8];
        bf16x8 b = *(const bf16x8*)&Wt2g[l15*64 + kc*32 + q*8];
        acc3 = __builtin_amdgcn_mfma_f32_16x16x32_bf16(a, b, acc3, 0, 0, 0);
    }
    if (l15 < NC) {
        float bias = b2[l15];
        #pragma unroll
        for (int rr = 0; rr < 4; ++rr) {
            out[(size_t)(row0 + wave*16 + q*4 + rr) * NC + l15] = acc3[rr] + bias;
        }
    }
}

extern "C" void kernel_launch(void* const* d_in, const int* in_sizes, int n_in,
                              void* d_out, int out_size, void* d_ws, size_t ws_size,
                              hipStream_t stream) {
    // inputs: 0=adj(unused) 1=features 2=W_emb 3=b_emb 4=W_rt1 5=b_rt1 6=W_rt2 7=b_rt2
    const float* F     = (const float*)d_in[1];
    const float* W_emb = (const float*)d_in[2];
    const float* b_emb = (const float*)d_in[3];
    const float* W_rt1 = (const float*)d_in[4];
    const float* b_rt1 = (const float*)d_in[5];
    const float* W_rt2 = (const float*)d_in[6];
    const float* b_rt2 = (const float*)d_in[7];
    u16* ws    = (u16*)d_ws;
    float* out = (float*)d_out;

    int prep_blocks = (WS_TOTAL + 255) / 256;
    prep_weights<<<prep_blocks, 256, 0, stream>>>(W_emb, W_rt1, W_rt2, ws);

    mlp_fused<<<N_NODES / BM, 256, 0, stream>>>(
        F, ws, ws + WS_WT1_OFF, ws + WS_WT2_OFF,
        b_emb, b_rt1, b_rt2, out);
}